// Round 3
// baseline (464.259 us; speedup 1.0000x reference)
//
#include <hip/hip_runtime.h>
#include <stdint.h>
#include <math.h>

#define N_CLS    81
#define TOPK     1000
#define LISTCAP  (1u << 21)     // 2M candidate keys (16 MB)
#define CAP2     16384          // final selection capacity
#define SCORE_TH 0.05f
#define IMG_W    1333.0f
#define IMG_H    800.0f
#define GH_REP   8              // coarse-hist replicas (atomic spread)

// coarse bucket = float_bits >> 19, range for (0.05, 1.0] is [1961, 2032]
#define GH_BASE  1905           // ghist index = (bits>>19) - GH_BASE, in [56,127]

// workspace layout (byte offsets)
#define OFF_CNT    0                       // u32 total candidates
#define OFF_CNT2   8                       // u32 selected count
#define OFF_TICK1  16                      // u32 K1 done-ticket
#define OFF_TICK2  20                      // u32 K2 done-ticket
#define OFF_SB     24                      // i32 coarse bucket B (-1 if < TOPK total)
#define OFF_CA     28                      // u32 count strictly above bucket B
#define OFF_TB     32                      // u32 exact threshold bits
#define OFF_GH     64                      // u32[GH_REP][128] coarse hist (4096 B)
#define OFF_RH     4608                    // u32[1024] refined hist (4096 B)
#define MEMSET_BYTES 8704
#define OFF_SEL    16768                   // u64[LISTCAP]
#define OFF_SEL2   16793984                // u64[CAP2]
#define OFF_BOX    16925056                // f32[1000*4]
#define OFF_SCORE  16941056                // f32[1000]
#define OFF_CLS    16945056                // i32[1000]
#define OFF_MASK   16949056                // u64[1000*16] conflict bit matrix

#define ROWS_PER_BLK 64
#define TILE_FLOATS  (ROWS_PER_BLK * N_CLS)   // 5184 floats = 20736 B (16B-aligned)

typedef unsigned long long u64;

// direct global->LDS 16B DMA (m97 pattern): LDS dest = wave-uniform base + lane*16
__device__ __forceinline__ void gload_lds16(const float* g, float* l) {
    __builtin_amdgcn_global_load_lds(
        (const __attribute__((address_space(1))) unsigned int*)g,
        (__attribute__((address_space(3))) unsigned int*)l, 16, 0, 0);
}

__device__ __forceinline__ unsigned agent_load_u32(const unsigned* p) {
    return __hip_atomic_load(p, __ATOMIC_RELAXED, __HIP_MEMORY_SCOPE_AGENT);
}

// ------- K1: 64-row LDS tile, pair-of-threads per row, direct wave-scan emit -------
// 21 KB LDS -> 7 blocks/CU (14 waves/CU). Per-row math is VERBATIM the verified
// bit-exact form (pair split by class parity; bitrev5 stack tree; shfl_xor(1)
// for max and top-level sum association). Last block (ticket) computes the
// coarse bucket B + c_above with a parallel suffix scan -> no per-block serial
// scan_coarse in later kernels.
__global__ __launch_bounds__(128) void k_pass1(
        const float* __restrict__ logits, int nrows,
        u64* __restrict__ sel, unsigned* __restrict__ cnt,
        unsigned* __restrict__ ghist, unsigned* __restrict__ tick,
        int* __restrict__ psB, unsigned* __restrict__ pCA) {
    __shared__ float tile[TILE_FLOATS];
    __shared__ unsigned lh[128];
    __shared__ unsigned scs[128], ssfx[128];
    __shared__ int wB;
    __shared__ unsigned wCA, tkt;
    int tid = threadIdx.x, wv = tid >> 6, ln = tid & 63;

    int base = blockIdx.x * ROWS_PER_BLK;
    int nr = nrows - base; if (nr > ROWS_PER_BLK) nr = ROWS_PER_BLK;
    const float* gtile = logits + (size_t)base * N_CLS;

    if (nr == ROWS_PER_BLK) {
        // 10 rounds x 2 waves x 1KB = 20480 B direct-to-LDS, + 256 B scalar tail
        #pragma unroll
        for (int it = 0; it < 10; ++it) {
            int c = it * 512 + wv * 256;           // float offset, wave-uniform
            gload_lds16(gtile + c + ln * 4, tile + c);
        }
        if (tid < 64) tile[5120 + tid] = gtile[5120 + tid];
    } else {
        for (int i = tid; i < nr * N_CLS; i += 128) tile[i] = gtile[i];
    }
    lh[tid] = 0;
    __syncthreads();   // drains vmcnt (global_load_lds) + lgkmcnt

    int r = tid >> 1, h = tid & 1;
    float v[41];
    float s = 1.0f;
    u64 bits = 0;
    if (r < nr) {
        const int rb = r * N_CLS + h;              // first owned class in LDS
        #pragma unroll
        for (int m = 0; m < 40; ++m) v[m] = tile[rb + 2 * m];
        v[40] = (h == 0) ? tile[rb + 80] : 0.0f;   // class 80 only exists for h=0

        // ---- row max (exact, order-free) ----
        float mx = v[0];
        #pragma unroll
        for (int m = 1; m < 40; ++m) mx = fmaxf(mx, v[m]);
        mx = fmaxf(mx, (h == 0) ? v[40] : v[0]);
        float om = __shfl_xor(mx, 1);
        float mrow = fmaxf(mx, om);

        // ---- exps (op-identical to reference kernel) ----
        #pragma unroll
        for (int m = 0; m < 40; ++m) v[m] = expf(v[m] - mrow);
        v[40] = (h == 0) ? expf(v[40] - mrow) : 0.0f;

        // ---- per-thread bitrev subtree over leaves l = h + 2*b ----
        float stk0 = 0.f, stk1 = 0.f, stk2 = 0.f, stk3 = 0.f, stk4 = 0.f;
        float S = 0.f;
        #pragma unroll
        for (int i = 0; i < 32; ++i) {
            const int b = ((i & 1) << 4) | ((i & 2) << 2) | (i & 4) |
                          ((i & 8) >> 2) | ((i & 16) >> 4);   // bitrev5(i)
            float x = v[b];
            if (b < 8) x += v[b + 32];
            else if (b == 8) x = (h == 0) ? x + v[40] : x;
            if (i & 1) { x = stk0 + x;
              if (i & 2) { x = stk1 + x;
                if (i & 4) { x = stk2 + x;
                  if (i & 8) { x = stk3 + x;
                    if (i & 16) { S = stk4 + x; } else stk4 = x;
                  } else stk3 = x;
                } else stk2 = x;
              } else stk1 = x;
            } else stk0 = x;
        }
        float oS = __shfl_xor(S, 1);
        s = (h == 0) ? (S + oS) : (oS + S);        // exact top-level association

        // ---- predicate bits: conservative pre-filter, then bit-exact p>0.05 ----
        float eth = 0.0499f * s;                   // 0.2% margin >> fp rounding
        #pragma unroll
        for (int m = 0; m < 41; ++m) {
            float e = v[m];
            if ((m + h) != 0 && e > eth) {         // skip background (h=0,m=0)
                float p = e / s;
                if (p > SCORE_TH) bits |= (1ull << m);
            }
        }
    }

    // ---- one atomic per wave: prefix-scan per-thread counts, scatter ----
    unsigned pc = (unsigned)__popcll(bits);
    unsigned scan = pc;
    #pragma unroll
    for (int off = 1; off < 64; off <<= 1) {
        unsigned t = __shfl_up(scan, off);
        if (ln >= off) scan += t;
    }
    unsigned wtotal = __shfl(scan, 63);
    unsigned wbase = 0;
    if (ln == 63 && wtotal) wbase = atomicAdd(cnt, wtotal);
    wbase = __shfl(wbase, 63);
    unsigned pos = wbase + scan - pc;
    unsigned rowflat = (unsigned)(base + r) * N_CLS + (unsigned)h;
    while (bits) {
        int m = (int)(__ffsll((unsigned long long)bits) - 1);
        bits &= bits - 1;
        float p = v[m] / s;                        // identical division
        unsigned fb = __float_as_uint(p);
        atomicAdd(&lh[(fb >> 19) - GH_BASE], 1u);
        if (pos < LISTCAP)
            sel[pos] = ((u64)fb << 32) | (u64)(0xFFFFFFu - (rowflat + 2u * (unsigned)m));
        pos++;
    }

    __syncthreads();
    { unsigned vv = lh[tid];
      if (vv) atomicAdd(&ghist[(blockIdx.x & (GH_REP - 1)) * 128 + tid], vv); }
    __threadfence();
    __syncthreads();
    if (tid == 0) tkt = atomicAdd(tick, 1u);
    __syncthreads();
    if (tkt != gridDim.x - 1) return;

    // ---- winner block: parallel coarse scan (replaces per-block scan_coarse) ----
    unsigned c = 0;
    #pragma unroll
    for (int rr = 0; rr < GH_REP; ++rr)
        c += agent_load_u32(&ghist[rr * 128 + tid]);
    scs[tid] = c; ssfx[tid] = c;
    if (tid == 0) wB = -1;
    __syncthreads();
    #pragma unroll
    for (int off = 1; off < 128; off <<= 1) {
        unsigned a = (tid + off < 128) ? ssfx[tid + off] : 0u;
        __syncthreads();
        ssfx[tid] += a;
        __syncthreads();
    }
    if (tid == 0) wCA = ssfx[0];                   // total (B<0 fallback)
    __syncthreads();
    unsigned incl = ssfx[tid], excl = incl - scs[tid];
    if (excl < TOPK && incl >= TOPK) { wB = tid; wCA = excl; }
    __syncthreads();
    if (tid == 0) { *psB = wB; *pCA = wCA; }
}

// ------- K2: refined 1024-bin hist inside bucket B; winner computes exact tb -------
__global__ __launch_bounds__(256) void k_refine(
        const u64* __restrict__ sel, const unsigned* __restrict__ cnt,
        unsigned* __restrict__ rhist, unsigned* __restrict__ tick,
        const int* __restrict__ psB, const unsigned* __restrict__ pCA,
        unsigned* __restrict__ ptb) {
    __shared__ unsigned lh[1024];
    __shared__ unsigned rbin[1024];
    __shared__ unsigned sgrp[256], ssfx[256];
    __shared__ int wg;
    __shared__ unsigned wcab, tkt;
    int tid = threadIdx.x;
    int B = *psB;
    if (B >= 0) {
        for (int i = tid; i < 1024; i += 256) lh[i] = 0;
        __syncthreads();
        unsigned Bbits = (unsigned)(B + GH_BASE);
        unsigned M = *cnt; if (M > LISTCAP) M = LISTCAP;
        unsigned stride = gridDim.x * blockDim.x;
        for (unsigned i = blockIdx.x * blockDim.x + tid; i < M; i += stride) {
            unsigned bv = (unsigned)(sel[i] >> 32);
            if ((bv >> 19) == Bbits) atomicAdd(&lh[(bv >> 9) & 1023u], 1u);
        }
        __syncthreads();
        for (int i = tid; i < 1024; i += 256) {
            unsigned vv = lh[i];
            if (vv) atomicAdd(&rhist[i], vv);
        }
    }
    __threadfence();
    __syncthreads();
    if (tid == 0) tkt = atomicAdd(tick, 1u);
    __syncthreads();
    if (tkt != gridDim.x - 1) return;

    // ---- winner: parallel exact-threshold find ----
    if (B < 0) { if (tid == 0) *ptb = 0u; return; }
    unsigned CA = *pCA;
    unsigned gsum = 0;
    #pragma unroll
    for (int k = 0; k < 4; ++k) {
        unsigned bv = agent_load_u32(&rhist[tid * 4 + k]);
        rbin[tid * 4 + k] = bv; gsum += bv;
    }
    sgrp[tid] = gsum; ssfx[tid] = gsum;
    if (tid == 0) wg = -1;
    __syncthreads();
    #pragma unroll
    for (int off = 1; off < 256; off <<= 1) {
        unsigned a = (tid + off < 256) ? ssfx[tid + off] : 0u;
        __syncthreads();
        ssfx[tid] += a;
        __syncthreads();
    }
    unsigned incl = ssfx[tid], excl = incl - sgrp[tid];
    if (CA + excl < TOPK && CA + incl >= TOPK) { wg = tid; wcab = CA + excl; }
    __syncthreads();
    if (tid == 0) {
        int g = wg; unsigned sb = 0;
        if (g >= 0) {
            unsigned cab = wcab;
            for (int i = g * 4 + 3; i >= g * 4; --i) {
                unsigned cc = rbin[i];
                if (cab + cc >= TOPK) { sb = (unsigned)i; break; }
                cab += cc;
            }
        }
        *ptb = ((unsigned)(B + GH_BASE) << 19) | (sb << 9);
    }
}

// ------- K3: compact keys >= tb into sel2 (tb precomputed -> pure streaming) -------
__global__ __launch_bounds__(256) void k_select(
        const u64* __restrict__ sel, const unsigned* __restrict__ cnt,
        const unsigned* __restrict__ ptb,
        u64* __restrict__ sel2, unsigned* __restrict__ cnt2) {
    int tid = threadIdx.x, ln = tid & 63;
    unsigned tb = *ptb;
    unsigned M = *cnt; if (M > LISTCAP) M = LISTCAP;
    unsigned stride = gridDim.x * blockDim.x;
    for (unsigned ibase = blockIdx.x * blockDim.x; ibase < M; ibase += stride) {
        unsigned i = ibase + tid;
        bool act = (i < M);
        u64 key = act ? sel[i] : 0ull;
        bool c = act && ((unsigned)(key >> 32) >= tb);
        u64 b = __ballot(c);
        int n = __popcll(b);
        if (n == 0) continue;
        unsigned wb = 0;
        if (ln == 0) wb = atomicAdd(cnt2, (unsigned)n);
        wb = __shfl(wb, 0);
        if (c) {
            unsigned pos = wb + (unsigned)__popcll(b & ((1ull << ln) - 1ull));
            if (pos < CAP2) sel2[pos] = key;
        }
    }
}

// ------- K4: exact rank by counting + fused decode (k_decode eliminated) -------
// Ranks of the S distinct keys are a bijection onto [0,S): thread t<S decodes
// its own key straight into slot r; threads t in [S,TOPK) write default slots.
__global__ __launch_bounds__(256) void k_rank_decode(
        const u64* __restrict__ sel2, const unsigned* __restrict__ cnt2,
        const float* __restrict__ boxes,
        float* __restrict__ boxK, float* __restrict__ scoreK, int* __restrict__ clsK) {
    __shared__ u64 ch[2048];
    unsigned S = *cnt2; if (S > CAP2) S = CAP2;
    unsigned t = blockIdx.x * 256u + threadIdx.x;
    if (blockIdx.x * 256u >= S) {                  // no ranking work in this block
        if (t < TOPK) {
            boxK[t * 4 + 0] = 0.0f; boxK[t * 4 + 1] = 0.0f;
            boxK[t * 4 + 2] = 0.0f; boxK[t * 4 + 3] = 0.0f;
            scoreK[t] = 0.0f; clsK[t] = -1;
        }
        return;
    }
    u64 my = (t < S) ? sel2[t] : 0ull;
    int r = 0;
    for (unsigned c0 = 0; c0 < S; c0 += 2048) {
        unsigned n = S - c0; if (n > 2048) n = 2048;
        __syncthreads();
        for (unsigned i = threadIdx.x; i < n; i += 256) ch[i] = sel2[c0 + i];
        __syncthreads();
        if (t < S)
            for (unsigned j = 0; j < n; j++) r += (ch[j] > my) ? 1 : 0;
    }
    if (t < S) {
        if (r < TOPK) {
            float sc = __uint_as_float((unsigned)(my >> 32));
            unsigned fi = 0xFFFFFFu - (unsigned)(my & 0xFFFFFFFFull);
            unsigned prop = fi / N_CLS;
            int cls = (int)(fi - prop * N_CLS);
            const float* b = boxes + (size_t)prop * 4;
            boxK[r * 4 + 0] = fminf(fmaxf(b[0], 0.0f), IMG_W - 1.0f);
            boxK[r * 4 + 1] = fminf(fmaxf(b[1], 0.0f), IMG_H - 1.0f);
            boxK[r * 4 + 2] = fminf(fmaxf(b[2], 0.0f), IMG_W - 1.0f);
            boxK[r * 4 + 3] = fminf(fmaxf(b[3], 0.0f), IMG_H - 1.0f);
            scoreK[r] = sc;
            clsK[r] = cls;
        }
    } else if (t < TOPK) {
        boxK[t * 4 + 0] = 0.0f; boxK[t * 4 + 1] = 0.0f;
        boxK[t * 4 + 2] = 0.0f; boxK[t * 4 + 3] = 0.0f;
        scoreK[t] = 0.0f; clsK[t] = -1;
    }
}

// ------- K5: conflict bit-matrix (IoU > 0.5 && same class), float4 loads -------
__global__ __launch_bounds__(256) void k_conflict(
        const float* __restrict__ boxK, const int* __restrict__ clsK,
        u64* __restrict__ mask) {
    int t = blockIdx.x * blockDim.x + threadIdx.x;
    if (t >= TOPK * 16) return;
    int i = t >> 4, w = t & 15;
    const float4* b4 = (const float4*)boxK;
    float4 bi = b4[i];
    int ci = clsK[i];
    float ai = (bi.z - bi.x) * (bi.w - bi.y);
    u64 m = 0;
    int jbase = w << 6;
    for (int jj = 0; jj < 64; jj++) {
        int j = jbase + jj;
        if (j >= TOPK) break;
        float4 bj = b4[j];
        float aj = (bj.z - bj.x) * (bj.w - bj.y);
        float ww = fmaxf(fminf(bi.z, bj.z) - fmaxf(bi.x, bj.x), 0.0f);
        float hh = fmaxf(fminf(bi.w, bj.w) - fmaxf(bi.y, bj.y), 0.0f);
        float inter = ww * hh;
        float iou = inter / (ai + aj - inter + 1e-9f);
        if (iou > 0.5f && ci == clsK[j]) m |= (1ull << jj);
    }
    mask[(size_t)i * 16 + w] = m;
}

// ------- K6: Jacobi fixed-point of the triangular greedy-NMS recurrence -------
__global__ __launch_bounds__(1024) void k_nms_out(
        const u64* __restrict__ mask, const float* __restrict__ boxK,
        const float* __restrict__ scoreK, float* __restrict__ out) {
    __shared__ u64 words[16];
    __shared__ int changed;
    int tid = threadIdx.x, wv = tid >> 6, ln = tid & 63;
    bool valid = (tid < TOPK) && (scoreK[tid] > 0.0f);
    u64 row[16];
    #pragma unroll
    for (int w = 0; w < 16; w++)
        row[w] = (tid < TOPK) ? mask[(size_t)tid * 16 + w] : 0ull;
    u64 lowmask = (1ull << ln) - 1ull;
    bool keep = valid;
    for (int it = 0; it < 1024; ++it) {
        u64 b = __ballot(keep);
        if (ln == 0) words[wv] = b;
        if (tid == 0) changed = 0;
        __syncthreads();
        u64 sup = 0;
        for (int w = 0; w <= wv; w++) {          // wv is wave-uniform
            u64 kw = words[w];
            if (w == wv) kw &= lowmask;
            sup |= row[w] & kw;
        }
        bool nk = valid && (sup == 0ull);
        if (nk != keep) changed = 1;
        keep = nk;
        __syncthreads();
        if (!changed) break;
    }
    if (tid < TOPK) {
        float x1 = boxK[tid * 4 + 0], y1 = boxK[tid * 4 + 1];
        float x2 = boxK[tid * 4 + 2], y2 = boxK[tid * 4 + 3];
        float sc = scoreK[tid];
        out[tid * 5 + 0] = keep ? x1 : 0.0f;
        out[tid * 5 + 1] = keep ? y1 : 0.0f;
        out[tid * 5 + 2] = keep ? x2 : 0.0f;
        out[tid * 5 + 3] = keep ? y2 : 0.0f;
        out[tid * 5 + 4] = keep ? sc : 0.0f;
    }
}

extern "C" void kernel_launch(void* const* d_in, const int* in_sizes, int n_in,
                              void* d_out, int out_size, void* d_ws, size_t ws_size,
                              hipStream_t stream) {
    const float* logits = (const float*)d_in[0];
    const float* boxes  = (const float*)d_in[1];
    float* out = (float*)d_out;
    int nrows = in_sizes[0] / N_CLS;   // 200000

    char* w = (char*)d_ws;
    unsigned* cnt    = (unsigned*)(w + OFF_CNT);
    unsigned* cnt2   = (unsigned*)(w + OFF_CNT2);
    unsigned* tick1  = (unsigned*)(w + OFF_TICK1);
    unsigned* tick2  = (unsigned*)(w + OFF_TICK2);
    int*      psB    = (int*)(w + OFF_SB);
    unsigned* pCA    = (unsigned*)(w + OFF_CA);
    unsigned* ptb    = (unsigned*)(w + OFF_TB);
    unsigned* ghist  = (unsigned*)(w + OFF_GH);
    unsigned* rhist  = (unsigned*)(w + OFF_RH);
    u64* sel         = (u64*)(w + OFF_SEL);
    u64* sel2        = (u64*)(w + OFF_SEL2);
    float* boxK      = (float*)(w + OFF_BOX);
    float* scoreK    = (float*)(w + OFF_SCORE);
    int* clsK        = (int*)(w + OFF_CLS);
    u64* mask        = (u64*)(w + OFF_MASK);

    hipMemsetAsync(w, 0, MEMSET_BYTES, stream);

    int nblk = (nrows + ROWS_PER_BLK - 1) / ROWS_PER_BLK;   // 3125
    k_pass1<<<nblk, 128, 0, stream>>>(logits, nrows, sel, cnt, ghist, tick1, psB, pCA);
    k_refine<<<256, 256, 0, stream>>>(sel, cnt, rhist, tick2, psB, pCA, ptb);
    k_select<<<256, 256, 0, stream>>>(sel, cnt, ptb, sel2, cnt2);
    k_rank_decode<<<CAP2 / 256, 256, 0, stream>>>(sel2, cnt2, boxes, boxK, scoreK, clsK);
    k_conflict<<<(TOPK * 16 + 255) / 256, 256, 0, stream>>>(boxK, clsK, mask);
    k_nms_out<<<1, 1024, 0, stream>>>(mask, boxK, scoreK, out);
}

// Round 4
// 433.820 us; speedup vs baseline: 1.0702x; 1.0702x over previous
//
#include <hip/hip_runtime.h>
#include <stdint.h>
#include <math.h>

#define N_CLS    81
#define TOPK     1000
#define LISTCAP  (1u << 21)     // 2M candidate keys (16 MB)
#define CAP2     16384          // final selection capacity
#define SCORE_TH 0.05f
#define IMG_W    1333.0f
#define IMG_H    800.0f
#define GH_REP   8              // coarse-hist replicas (atomic spread)

// coarse bucket = float_bits >> 19, range for (0.05, 1.0] is [1961, 2032]
#define GH_BASE  1905           // ghist index = (bits>>19) - GH_BASE, in [56,127]

// workspace layout (byte offsets)
#define OFF_CNT    0                       // u32 total candidates
#define OFF_CNT2   8                       // u32 selected count
#define OFF_TICK1  16                      // u32 K1 done-ticket
#define OFF_TICK2  20                      // u32 K2 done-ticket
#define OFF_SB     24                      // i32 coarse bucket B (-1 if < TOPK total)
#define OFF_CA     28                      // u32 count strictly above bucket B
#define OFF_TB     32                      // u32 exact threshold bits
#define OFF_GH     64                      // u32[GH_REP][128] coarse hist (4096 B)
#define OFF_RH     4608                    // u32[1024] refined hist (4096 B)
#define MEMSET_BYTES 8704
#define OFF_SEL    16768                   // u64[LISTCAP]
#define OFF_SEL2   16793984                // u64[CAP2]
#define OFF_BOX    16925056                // f32[1000*4]
#define OFF_SCORE  16941056                // f32[1000]
#define OFF_CLS    16945056                // i32[1000]
#define OFF_MASK   16949056                // u64[1000*16] conflict bit matrix

#define ROWS_PER_BLK 64
#define TILE_FLOATS  (ROWS_PER_BLK * N_CLS)   // 5184 floats = 20736 B (16B-aligned)

typedef unsigned long long u64;

// direct global->LDS 16B DMA (m97 pattern): LDS dest = wave-uniform base + lane*16
__device__ __forceinline__ void gload_lds16(const float* g, float* l) {
    __builtin_amdgcn_global_load_lds(
        (const __attribute__((address_space(1))) unsigned int*)g,
        (__attribute__((address_space(3))) unsigned int*)l, 16, 0, 0);
}

__device__ __forceinline__ unsigned agent_load_u32(const unsigned* p) {
    return __hip_atomic_load(p, __ATOMIC_RELAXED, __HIP_MEMORY_SCOPE_AGENT);
}

// ------- K1: 64-row LDS tile, pair-of-threads per row, direct wave-scan emit -------
// 21 KB LDS -> 7 blocks/CU (14 waves/CU). Per-row math is VERBATIM the verified
// bit-exact form (pair split by class parity; bitrev5 stack tree; shfl_xor(1)
// for max and top-level sum association). Emit loop uses COMPILE-TIME indices
// only (rule #20: runtime-indexed v[] spills the whole array to scratch --
// round-3's while(ffs) loop cost 65 MB of scratch traffic, 290 us).
__global__ __launch_bounds__(128) void k_pass1(
        const float* __restrict__ logits, int nrows,
        u64* __restrict__ sel, unsigned* __restrict__ cnt,
        unsigned* __restrict__ ghist, unsigned* __restrict__ tick,
        int* __restrict__ psB, unsigned* __restrict__ pCA) {
    __shared__ float tile[TILE_FLOATS];
    __shared__ unsigned lh[128];
    __shared__ unsigned scs[128], ssfx[128];
    __shared__ int wB;
    __shared__ unsigned wCA, tkt;
    int tid = threadIdx.x, wv = tid >> 6, ln = tid & 63;

    int base = blockIdx.x * ROWS_PER_BLK;
    int nr = nrows - base; if (nr > ROWS_PER_BLK) nr = ROWS_PER_BLK;
    const float* gtile = logits + (size_t)base * N_CLS;

    if (nr == ROWS_PER_BLK) {
        // 10 rounds x 2 waves x 1KB = 20480 B direct-to-LDS, + 256 B scalar tail
        #pragma unroll
        for (int it = 0; it < 10; ++it) {
            int c = it * 512 + wv * 256;           // float offset, wave-uniform
            gload_lds16(gtile + c + ln * 4, tile + c);
        }
        if (tid < 64) tile[5120 + tid] = gtile[5120 + tid];
    } else {
        for (int i = tid; i < nr * N_CLS; i += 128) tile[i] = gtile[i];
    }
    lh[tid] = 0;
    __syncthreads();   // drains vmcnt (global_load_lds) + lgkmcnt

    int r = tid >> 1, h = tid & 1;
    float v[41];
    float s = 1.0f;
    u64 bits = 0;
    if (r < nr) {
        const int rb = r * N_CLS + h;              // first owned class in LDS
        #pragma unroll
        for (int m = 0; m < 40; ++m) v[m] = tile[rb + 2 * m];
        v[40] = (h == 0) ? tile[rb + 80] : 0.0f;   // class 80 only exists for h=0

        // ---- row max (exact, order-free) ----
        float mx = v[0];
        #pragma unroll
        for (int m = 1; m < 40; ++m) mx = fmaxf(mx, v[m]);
        mx = fmaxf(mx, (h == 0) ? v[40] : v[0]);
        float om = __shfl_xor(mx, 1);
        float mrow = fmaxf(mx, om);

        // ---- exps (op-identical to reference kernel) ----
        #pragma unroll
        for (int m = 0; m < 40; ++m) v[m] = expf(v[m] - mrow);
        v[40] = (h == 0) ? expf(v[40] - mrow) : 0.0f;

        // ---- per-thread bitrev subtree over leaves l = h + 2*b ----
        float stk0 = 0.f, stk1 = 0.f, stk2 = 0.f, stk3 = 0.f, stk4 = 0.f;
        float S = 0.f;
        #pragma unroll
        for (int i = 0; i < 32; ++i) {
            const int b = ((i & 1) << 4) | ((i & 2) << 2) | (i & 4) |
                          ((i & 8) >> 2) | ((i & 16) >> 4);   // bitrev5(i)
            float x = v[b];
            if (b < 8) x += v[b + 32];
            else if (b == 8) x = (h == 0) ? x + v[40] : x;
            if (i & 1) { x = stk0 + x;
              if (i & 2) { x = stk1 + x;
                if (i & 4) { x = stk2 + x;
                  if (i & 8) { x = stk3 + x;
                    if (i & 16) { S = stk4 + x; } else stk4 = x;
                  } else stk3 = x;
                } else stk2 = x;
              } else stk1 = x;
            } else stk0 = x;
        }
        float oS = __shfl_xor(S, 1);
        s = (h == 0) ? (S + oS) : (oS + S);        // exact top-level association

        // ---- predicate bits: conservative pre-filter, then bit-exact p>0.05 ----
        float eth = 0.0499f * s;                   // 0.2% margin >> fp rounding
        #pragma unroll
        for (int m = 0; m < 41; ++m) {
            float e = v[m];
            if ((m + h) != 0 && e > eth) {         // skip background (h=0,m=0)
                float p = e / s;
                if (p > SCORE_TH) bits |= (1ull << m);
            }
        }
    }

    // ---- one atomic per wave: prefix-scan per-thread counts, scatter ----
    unsigned pc = (unsigned)__popcll(bits);
    unsigned scan = pc;
    #pragma unroll
    for (int off = 1; off < 64; off <<= 1) {
        unsigned t = __shfl_up(scan, off);
        if (ln >= off) scan += t;
    }
    unsigned wtotal = __shfl(scan, 63);
    unsigned wbase = 0;
    if (ln == 63 && wtotal) wbase = atomicAdd(cnt, wtotal);
    wbase = __shfl(wbase, 63);
    unsigned pos = wbase + scan - pc;
    unsigned rowflat = (unsigned)(base + r) * N_CLS + (unsigned)h;
    // COMPILE-TIME index m (ascending, same order/positions as before)
    #pragma unroll
    for (int m = 0; m < 41; ++m) {
        if (bits & (1ull << m)) {
            float p = v[m] / s;                    // identical division
            unsigned fb = __float_as_uint(p);
            atomicAdd(&lh[(fb >> 19) - GH_BASE], 1u);
            if (pos < LISTCAP)
                sel[pos] = ((u64)fb << 32) | (u64)(0xFFFFFFu - (rowflat + 2u * (unsigned)m));
            pos++;
        }
    }

    __syncthreads();
    { unsigned vv = lh[tid];
      if (vv) atomicAdd(&ghist[(blockIdx.x & (GH_REP - 1)) * 128 + tid], vv); }
    __threadfence();
    __syncthreads();
    if (tid == 0) tkt = atomicAdd(tick, 1u);
    __syncthreads();
    if (tkt != gridDim.x - 1) return;

    // ---- winner block: parallel coarse scan (replaces per-block scan_coarse) ----
    unsigned c = 0;
    #pragma unroll
    for (int rr = 0; rr < GH_REP; ++rr)
        c += agent_load_u32(&ghist[rr * 128 + tid]);
    scs[tid] = c; ssfx[tid] = c;
    if (tid == 0) wB = -1;
    __syncthreads();
    #pragma unroll
    for (int off = 1; off < 128; off <<= 1) {
        unsigned a = (tid + off < 128) ? ssfx[tid + off] : 0u;
        __syncthreads();
        ssfx[tid] += a;
        __syncthreads();
    }
    if (tid == 0) wCA = ssfx[0];                   // total (B<0 fallback)
    __syncthreads();
    unsigned incl = ssfx[tid], excl = incl - scs[tid];
    if (excl < TOPK && incl >= TOPK) { wB = tid; wCA = excl; }
    __syncthreads();
    if (tid == 0) { *psB = wB; *pCA = wCA; }
}

// ------- K2: refined 1024-bin hist inside bucket B; winner computes exact tb -------
__global__ __launch_bounds__(256) void k_refine(
        const u64* __restrict__ sel, const unsigned* __restrict__ cnt,
        unsigned* __restrict__ rhist, unsigned* __restrict__ tick,
        const int* __restrict__ psB, const unsigned* __restrict__ pCA,
        unsigned* __restrict__ ptb) {
    __shared__ unsigned lh[1024];
    __shared__ unsigned rbin[1024];
    __shared__ unsigned sgrp[256], ssfx[256];
    __shared__ int wg;
    __shared__ unsigned wcab, tkt;
    int tid = threadIdx.x;
    int B = *psB;
    if (B >= 0) {
        for (int i = tid; i < 1024; i += 256) lh[i] = 0;
        __syncthreads();
        unsigned Bbits = (unsigned)(B + GH_BASE);
        unsigned M = *cnt; if (M > LISTCAP) M = LISTCAP;
        unsigned stride = gridDim.x * blockDim.x;
        for (unsigned i = blockIdx.x * blockDim.x + tid; i < M; i += stride) {
            unsigned bv = (unsigned)(sel[i] >> 32);
            if ((bv >> 19) == Bbits) atomicAdd(&lh[(bv >> 9) & 1023u], 1u);
        }
        __syncthreads();
        for (int i = tid; i < 1024; i += 256) {
            unsigned vv = lh[i];
            if (vv) atomicAdd(&rhist[i], vv);
        }
    }
    __threadfence();
    __syncthreads();
    if (tid == 0) tkt = atomicAdd(tick, 1u);
    __syncthreads();
    if (tkt != gridDim.x - 1) return;

    // ---- winner: parallel exact-threshold find ----
    if (B < 0) { if (tid == 0) *ptb = 0u; return; }
    unsigned CA = *pCA;
    unsigned gsum = 0;
    #pragma unroll
    for (int k = 0; k < 4; ++k) {
        unsigned bv = agent_load_u32(&rhist[tid * 4 + k]);
        rbin[tid * 4 + k] = bv; gsum += bv;
    }
    sgrp[tid] = gsum; ssfx[tid] = gsum;
    if (tid == 0) wg = -1;
    __syncthreads();
    #pragma unroll
    for (int off = 1; off < 256; off <<= 1) {
        unsigned a = (tid + off < 256) ? ssfx[tid + off] : 0u;
        __syncthreads();
        ssfx[tid] += a;
        __syncthreads();
    }
    unsigned incl = ssfx[tid], excl = incl - sgrp[tid];
    if (CA + excl < TOPK && CA + incl >= TOPK) { wg = tid; wcab = CA + excl; }
    __syncthreads();
    if (tid == 0) {
        int g = wg; unsigned sb = 0;
        if (g >= 0) {
            unsigned cab = wcab;
            for (int i = g * 4 + 3; i >= g * 4; --i) {
                unsigned cc = rbin[i];
                if (cab + cc >= TOPK) { sb = (unsigned)i; break; }
                cab += cc;
            }
        }
        *ptb = ((unsigned)(B + GH_BASE) << 19) | (sb << 9);
    }
}

// ------- K3: compact keys >= tb into sel2 (tb precomputed -> pure streaming) -------
__global__ __launch_bounds__(256) void k_select(
        const u64* __restrict__ sel, const unsigned* __restrict__ cnt,
        const unsigned* __restrict__ ptb,
        u64* __restrict__ sel2, unsigned* __restrict__ cnt2) {
    int tid = threadIdx.x, ln = tid & 63;
    unsigned tb = *ptb;
    unsigned M = *cnt; if (M > LISTCAP) M = LISTCAP;
    unsigned stride = gridDim.x * blockDim.x;
    for (unsigned ibase = blockIdx.x * blockDim.x; ibase < M; ibase += stride) {
        unsigned i = ibase + tid;
        bool act = (i < M);
        u64 key = act ? sel[i] : 0ull;
        bool c = act && ((unsigned)(key >> 32) >= tb);
        u64 b = __ballot(c);
        int n = __popcll(b);
        if (n == 0) continue;
        unsigned wb = 0;
        if (ln == 0) wb = atomicAdd(cnt2, (unsigned)n);
        wb = __shfl(wb, 0);
        if (c) {
            unsigned pos = wb + (unsigned)__popcll(b & ((1ull << ln) - 1ull));
            if (pos < CAP2) sel2[pos] = key;
        }
    }
}

// ------- K4: exact rank by counting + fused decode (k_decode eliminated) -------
// Ranks of the S distinct keys are a bijection onto [0,S): thread t<S decodes
// its own key straight into slot r; threads t in [S,TOPK) write default slots.
__global__ __launch_bounds__(256) void k_rank_decode(
        const u64* __restrict__ sel2, const unsigned* __restrict__ cnt2,
        const float* __restrict__ boxes,
        float* __restrict__ boxK, float* __restrict__ scoreK, int* __restrict__ clsK) {
    __shared__ u64 ch[2048];
    unsigned S = *cnt2; if (S > CAP2) S = CAP2;
    unsigned t = blockIdx.x * 256u + threadIdx.x;
    if (blockIdx.x * 256u >= S) {                  // no ranking work in this block
        if (t < TOPK) {
            boxK[t * 4 + 0] = 0.0f; boxK[t * 4 + 1] = 0.0f;
            boxK[t * 4 + 2] = 0.0f; boxK[t * 4 + 3] = 0.0f;
            scoreK[t] = 0.0f; clsK[t] = -1;
        }
        return;
    }
    u64 my = (t < S) ? sel2[t] : 0ull;
    int r = 0;
    for (unsigned c0 = 0; c0 < S; c0 += 2048) {
        unsigned n = S - c0; if (n > 2048) n = 2048;
        __syncthreads();
        for (unsigned i = threadIdx.x; i < n; i += 256) ch[i] = sel2[c0 + i];
        __syncthreads();
        if (t < S)
            for (unsigned j = 0; j < n; j++) r += (ch[j] > my) ? 1 : 0;
    }
    if (t < S) {
        if (r < TOPK) {
            float sc = __uint_as_float((unsigned)(my >> 32));
            unsigned fi = 0xFFFFFFu - (unsigned)(my & 0xFFFFFFFFull);
            unsigned prop = fi / N_CLS;
            int cls = (int)(fi - prop * N_CLS);
            const float* b = boxes + (size_t)prop * 4;
            boxK[r * 4 + 0] = fminf(fmaxf(b[0], 0.0f), IMG_W - 1.0f);
            boxK[r * 4 + 1] = fminf(fmaxf(b[1], 0.0f), IMG_H - 1.0f);
            boxK[r * 4 + 2] = fminf(fmaxf(b[2], 0.0f), IMG_W - 1.0f);
            boxK[r * 4 + 3] = fminf(fmaxf(b[3], 0.0f), IMG_H - 1.0f);
            scoreK[r] = sc;
            clsK[r] = cls;
        }
    } else if (t < TOPK) {
        boxK[t * 4 + 0] = 0.0f; boxK[t * 4 + 1] = 0.0f;
        boxK[t * 4 + 2] = 0.0f; boxK[t * 4 + 3] = 0.0f;
        scoreK[t] = 0.0f; clsK[t] = -1;
    }
}

// ------- K5: conflict bit-matrix (IoU > 0.5 && same class), float4 loads -------
__global__ __launch_bounds__(256) void k_conflict(
        const float* __restrict__ boxK, const int* __restrict__ clsK,
        u64* __restrict__ mask) {
    int t = blockIdx.x * blockDim.x + threadIdx.x;
    if (t >= TOPK * 16) return;
    int i = t >> 4, w = t & 15;
    const float4* b4 = (const float4*)boxK;
    float4 bi = b4[i];
    int ci = clsK[i];
    float ai = (bi.z - bi.x) * (bi.w - bi.y);
    u64 m = 0;
    int jbase = w << 6;
    for (int jj = 0; jj < 64; jj++) {
        int j = jbase + jj;
        if (j >= TOPK) break;
        float4 bj = b4[j];
        float aj = (bj.z - bj.x) * (bj.w - bj.y);
        float ww = fmaxf(fminf(bi.z, bj.z) - fmaxf(bi.x, bj.x), 0.0f);
        float hh = fmaxf(fminf(bi.w, bj.w) - fmaxf(bi.y, bj.y), 0.0f);
        float inter = ww * hh;
        float iou = inter / (ai + aj - inter + 1e-9f);
        if (iou > 0.5f && ci == clsK[j]) m |= (1ull << jj);
    }
    mask[(size_t)i * 16 + w] = m;
}

// ------- K6: Jacobi fixed-point of the triangular greedy-NMS recurrence -------
__global__ __launch_bounds__(1024) void k_nms_out(
        const u64* __restrict__ mask, const float* __restrict__ boxK,
        const float* __restrict__ scoreK, float* __restrict__ out) {
    __shared__ u64 words[16];
    __shared__ int changed;
    int tid = threadIdx.x, wv = tid >> 6, ln = tid & 63;
    bool valid = (tid < TOPK) && (scoreK[tid] > 0.0f);
    u64 row[16];
    #pragma unroll
    for (int w = 0; w < 16; w++)
        row[w] = (tid < TOPK) ? mask[(size_t)tid * 16 + w] : 0ull;
    u64 lowmask = (1ull << ln) - 1ull;
    bool keep = valid;
    for (int it = 0; it < 1024; ++it) {
        u64 b = __ballot(keep);
        if (ln == 0) words[wv] = b;
        if (tid == 0) changed = 0;
        __syncthreads();
        u64 sup = 0;
        for (int w = 0; w <= wv; w++) {          // wv is wave-uniform
            u64 kw = words[w];
            if (w == wv) kw &= lowmask;
            sup |= row[w] & kw;
        }
        bool nk = valid && (sup == 0ull);
        if (nk != keep) changed = 1;
        keep = nk;
        __syncthreads();
        if (!changed) break;
    }
    if (tid < TOPK) {
        float x1 = boxK[tid * 4 + 0], y1 = boxK[tid * 4 + 1];
        float x2 = boxK[tid * 4 + 2], y2 = boxK[tid * 4 + 3];
        float sc = scoreK[tid];
        out[tid * 5 + 0] = keep ? x1 : 0.0f;
        out[tid * 5 + 1] = keep ? y1 : 0.0f;
        out[tid * 5 + 2] = keep ? x2 : 0.0f;
        out[tid * 5 + 3] = keep ? y2 : 0.0f;
        out[tid * 5 + 4] = keep ? sc : 0.0f;
    }
}

extern "C" void kernel_launch(void* const* d_in, const int* in_sizes, int n_in,
                              void* d_out, int out_size, void* d_ws, size_t ws_size,
                              hipStream_t stream) {
    const float* logits = (const float*)d_in[0];
    const float* boxes  = (const float*)d_in[1];
    float* out = (float*)d_out;
    int nrows = in_sizes[0] / N_CLS;   // 200000

    char* w = (char*)d_ws;
    unsigned* cnt    = (unsigned*)(w + OFF_CNT);
    unsigned* cnt2   = (unsigned*)(w + OFF_CNT2);
    unsigned* tick1  = (unsigned*)(w + OFF_TICK1);
    unsigned* tick2  = (unsigned*)(w + OFF_TICK2);
    int*      psB    = (int*)(w + OFF_SB);
    unsigned* pCA    = (unsigned*)(w + OFF_CA);
    unsigned* ptb    = (unsigned*)(w + OFF_TB);
    unsigned* ghist  = (unsigned*)(w + OFF_GH);
    unsigned* rhist  = (unsigned*)(w + OFF_RH);
    u64* sel         = (u64*)(w + OFF_SEL);
    u64* sel2        = (u64*)(w + OFF_SEL2);
    float* boxK      = (float*)(w + OFF_BOX);
    float* scoreK    = (float*)(w + OFF_SCORE);
    int* clsK        = (int*)(w + OFF_CLS);
    u64* mask        = (u64*)(w + OFF_MASK);

    hipMemsetAsync(w, 0, MEMSET_BYTES, stream);

    int nblk = (nrows + ROWS_PER_BLK - 1) / ROWS_PER_BLK;   // 3125
    k_pass1<<<nblk, 128, 0, stream>>>(logits, nrows, sel, cnt, ghist, tick1, psB, pCA);
    k_refine<<<256, 256, 0, stream>>>(sel, cnt, rhist, tick2, psB, pCA, ptb);
    k_select<<<256, 256, 0, stream>>>(sel, cnt, ptb, sel2, cnt2);
    k_rank_decode<<<CAP2 / 256, 256, 0, stream>>>(sel2, cnt2, boxes, boxK, scoreK, clsK);
    k_conflict<<<(TOPK * 16 + 255) / 256, 256, 0, stream>>>(boxK, clsK, mask);
    k_nms_out<<<1, 1024, 0, stream>>>(mask, boxK, scoreK, out);
}

// Round 5
// 322.441 us; speedup vs baseline: 1.4398x; 1.3454x over previous
//
#include <hip/hip_runtime.h>
#include <stdint.h>
#include <math.h>

#define N_CLS    81
#define TOPK     1000
#define LISTCAP  (1u << 21)     // 2M candidate keys (16 MB)
#define CAP2     16384          // final selection capacity
#define SCORE_TH 0.05f
#define IMG_W    1333.0f
#define IMG_H    800.0f
#define GH_REP   8              // coarse-hist replicas (atomic spread)

// coarse bucket = float_bits >> 19, range for (0.05, 1.0] is [1961, 2032]
#define GH_BASE  1905           // ghist index = (bits>>19) - GH_BASE, in [56,127]

// workspace layout (byte offsets)
#define OFF_CNT    0                       // u32 total candidates
#define OFF_CNT2   8                       // u32 selected count
#define OFF_TICK1  16                      // u32 K1 done-ticket
#define OFF_TICK2  20                      // u32 K2 done-ticket
#define OFF_SB     24                      // i32 coarse bucket B (-1 if < TOPK total)
#define OFF_CA     28                      // u32 count strictly above bucket B
#define OFF_TB     32                      // u32 exact threshold bits
#define OFF_GH     64                      // u32[GH_REP][128] coarse hist (4096 B)
#define OFF_RH     4608                    // u32[1024] refined hist (4096 B)
#define MEMSET_BYTES 8704
#define OFF_SEL    16768                   // u64[LISTCAP]
#define OFF_SEL2   16793984                // u64[CAP2]
#define OFF_BOX    16925056                // f32[1000*4]
#define OFF_SCORE  16941056                // f32[1000]
#define OFF_CLS    16945056                // i32[1000]
#define OFF_MASK   16949056                // u64[1000*16] conflict bit matrix

#define GRP_ROWS   32                      // rows per wave-group (64 lanes / 2)
#define GRP_FLOATS (GRP_ROWS * N_CLS)      // 2592 floats = 10368 B per wave strip

typedef unsigned long long u64;

// direct global->LDS 16B DMA: LDS dest = wave-uniform base + lane*16
__device__ __forceinline__ void gload_lds16(const float* g, float* l) {
    __builtin_amdgcn_global_load_lds(
        (const __attribute__((address_space(1))) unsigned int*)g,
        (__attribute__((address_space(3))) unsigned int*)l, 16, 0, 0);
}

__device__ __forceinline__ unsigned agent_load_u32(const unsigned* p) {
    return __hip_atomic_load(p, __ATOMIC_RELAXED, __HIP_MEMORY_SCOPE_AGENT);
}

// ------- K1: wave-autonomous pipelines; pair-of-threads per row -------
// 256-thr blocks (__launch_bounds__(256) == the VGPR-68 no-spill builds;
// the 128-thr rounds spilled v[41] at a 52-VGPR cap). Each wave owns a
// private 10.4 KB LDS strip and grid-strides over 32-row groups: stage via
// global_load_lds -> wave-local vmcnt(0) -> compute -> emit. NO block
// barrier in the main loop: 12 wave-pipelines/CU self-overlap DMA+compute.
// Math is VERBATIM the verified bit-exact form (class-parity pair split,
// bitrev5 stack tree, shfl_xor(1) for max and top-level sum association).
__global__ __launch_bounds__(256) void k_pass1(
        const float* __restrict__ logits, int nrows,
        u64* __restrict__ sel, unsigned* __restrict__ cnt,
        unsigned* __restrict__ ghist, unsigned* __restrict__ tick,
        int* __restrict__ psB, unsigned* __restrict__ pCA) {
    __shared__ float tile[4][GRP_FLOATS];          // 41472 B (wave-private strips)
    __shared__ unsigned lh[128];
    __shared__ unsigned scs[128], ssfx[128];
    __shared__ int wB;
    __shared__ unsigned wCA, tkt;
    int tid = threadIdx.x, wv = tid >> 6, ln = tid & 63;
    if (tid < 128) lh[tid] = 0;
    __syncthreads();                               // lh visible before any emit

    float* wbuf = tile[wv];
    int ngrp = (nrows + GRP_ROWS - 1) / GRP_ROWS;
    int r = ln >> 1, h = ln & 1;                   // local row in group, parity

    for (int grp = blockIdx.x * 4 + wv; grp < ngrp; grp += gridDim.x * 4) {
        int base = grp * GRP_ROWS;
        int nr = nrows - base; if (nr > GRP_ROWS) nr = GRP_ROWS;
        const float* g = logits + (size_t)base * N_CLS;

        __builtin_amdgcn_sched_barrier(0);         // keep stage after prior reads
        if (nr == GRP_ROWS) {
            // 10 x 1KB direct-to-LDS + 32-float scalar tail (2592 = 10*256+32)
            #pragma unroll
            for (int it = 0; it < 10; ++it)
                gload_lds16(g + it * 256 + ln * 4, wbuf + it * 256);
            if (ln < 32) wbuf[2560 + ln] = g[2560 + ln];
            asm volatile("s_waitcnt vmcnt(0)" ::: "memory");   // wave-local drain
            __builtin_amdgcn_sched_barrier(0);
        } else {
            for (int i = ln; i < nr * N_CLS; i += 64) wbuf[i] = g[i];
        }

        float v[41];
        float s = 1.0f;
        u64 bits = 0;
        if (r < nr) {
            const int rb = r * N_CLS + h;          // first owned class in strip
            #pragma unroll
            for (int m = 0; m < 40; ++m) v[m] = wbuf[rb + 2 * m];
            v[40] = (h == 0) ? wbuf[rb + 80] : 0.0f;

            // ---- row max (exact, order-free) ----
            float mx = v[0];
            #pragma unroll
            for (int m = 1; m < 40; ++m) mx = fmaxf(mx, v[m]);
            mx = fmaxf(mx, (h == 0) ? v[40] : v[0]);
            float om = __shfl_xor(mx, 1);
            float mrow = fmaxf(mx, om);

            // ---- exps (op-identical to reference kernel) ----
            #pragma unroll
            for (int m = 0; m < 40; ++m) v[m] = expf(v[m] - mrow);
            v[40] = (h == 0) ? expf(v[40] - mrow) : 0.0f;

            // ---- per-thread bitrev subtree over leaves l = h + 2*b ----
            float stk0 = 0.f, stk1 = 0.f, stk2 = 0.f, stk3 = 0.f, stk4 = 0.f;
            float S = 0.f;
            #pragma unroll
            for (int i = 0; i < 32; ++i) {
                const int b = ((i & 1) << 4) | ((i & 2) << 2) | (i & 4) |
                              ((i & 8) >> 2) | ((i & 16) >> 4);   // bitrev5(i)
                float x = v[b];
                if (b < 8) x += v[b + 32];
                else if (b == 8) x = (h == 0) ? x + v[40] : x;
                if (i & 1) { x = stk0 + x;
                  if (i & 2) { x = stk1 + x;
                    if (i & 4) { x = stk2 + x;
                      if (i & 8) { x = stk3 + x;
                        if (i & 16) { S = stk4 + x; } else stk4 = x;
                      } else stk4 = stk4, stk3 = x;
                    } else stk2 = x;
                  } else stk1 = x;
                } else stk0 = x;
            }
            float oS = __shfl_xor(S, 1);
            s = (h == 0) ? (S + oS) : (oS + S);    // exact top-level association

            // ---- predicate: conservative pre-filter, then bit-exact p>0.05 ----
            float eth = 0.0499f * s;               // 0.2% margin >> fp rounding
            #pragma unroll
            for (int m = 0; m < 41; ++m) {
                float e = v[m];
                if ((m + h) != 0 && e > eth) {     // skip background (h=0,m=0)
                    float p = e / s;
                    if (p > SCORE_TH) bits |= (1ull << m);
                }
            }
        }

        // ---- one atomic per wave-group: prefix-scan counts, scatter ----
        unsigned pc = (unsigned)__popcll(bits);
        unsigned scan = pc;
        #pragma unroll
        for (int off = 1; off < 64; off <<= 1) {
            unsigned t = __shfl_up(scan, off);
            if (ln >= off) scan += t;
        }
        unsigned wtotal = __shfl(scan, 63);
        unsigned wbase = 0;
        if (ln == 63 && wtotal) wbase = atomicAdd(cnt, wtotal);
        wbase = __shfl(wbase, 63);
        unsigned pos = wbase + scan - pc;
        unsigned rowflat = (unsigned)(base + r) * N_CLS + (unsigned)h;
        #pragma unroll
        for (int m = 0; m < 41; ++m) {             // COMPILE-TIME v[] index only
            if (bits & (1ull << m)) {
                float p = v[m] / s;                // identical division
                unsigned fb = __float_as_uint(p);
                atomicAdd(&lh[(fb >> 19) - GH_BASE], 1u);
                if (pos < LISTCAP)
                    sel[pos] = ((u64)fb << 32) |
                               (u64)(0xFFFFFFu - (rowflat + 2u * (unsigned)m));
                pos++;
            }
        }
    }

    __syncthreads();
    if (tid < 128) {
        unsigned vv = lh[tid];
        if (vv) atomicAdd(&ghist[(blockIdx.x & (GH_REP - 1)) * 128 + tid], vv);
    }
    __threadfence();
    __syncthreads();
    if (tid == 0) tkt = atomicAdd(tick, 1u);
    __syncthreads();
    if (tkt != gridDim.x - 1) return;

    // ---- winner block: parallel coarse scan (guarded for 256 threads) ----
    if (tid < 128) {
        unsigned c = 0;
        #pragma unroll
        for (int rr = 0; rr < GH_REP; ++rr)
            c += agent_load_u32(&ghist[rr * 128 + tid]);
        scs[tid] = c; ssfx[tid] = c;
    }
    if (tid == 0) wB = -1;
    __syncthreads();
    #pragma unroll
    for (int off = 1; off < 128; off <<= 1) {
        unsigned a = 0;
        if (tid < 128) a = (tid + off < 128) ? ssfx[tid + off] : 0u;
        __syncthreads();
        if (tid < 128) ssfx[tid] += a;
        __syncthreads();
    }
    if (tid == 0) wCA = ssfx[0];                   // total (B<0 fallback)
    __syncthreads();
    if (tid < 128) {
        unsigned incl = ssfx[tid], excl = incl - scs[tid];
        if (excl < TOPK && incl >= TOPK) { wB = tid; wCA = excl; }
    }
    __syncthreads();
    if (tid == 0) { *psB = wB; *pCA = wCA; }
}

// ------- K2: refined 1024-bin hist inside bucket B; winner computes exact tb -------
__global__ __launch_bounds__(256) void k_refine(
        const u64* __restrict__ sel, const unsigned* __restrict__ cnt,
        unsigned* __restrict__ rhist, unsigned* __restrict__ tick,
        const int* __restrict__ psB, const unsigned* __restrict__ pCA,
        unsigned* __restrict__ ptb) {
    __shared__ unsigned lh[1024];
    __shared__ unsigned rbin[1024];
    __shared__ unsigned sgrp[256], ssfx[256];
    __shared__ int wg;
    __shared__ unsigned wcab, tkt;
    int tid = threadIdx.x;
    int B = *psB;
    if (B >= 0) {
        for (int i = tid; i < 1024; i += 256) lh[i] = 0;
        __syncthreads();
        unsigned Bbits = (unsigned)(B + GH_BASE);
        unsigned M = *cnt; if (M > LISTCAP) M = LISTCAP;
        unsigned stride = gridDim.x * blockDim.x;
        for (unsigned i = blockIdx.x * blockDim.x + tid; i < M; i += stride) {
            unsigned bv = (unsigned)(sel[i] >> 32);
            if ((bv >> 19) == Bbits) atomicAdd(&lh[(bv >> 9) & 1023u], 1u);
        }
        __syncthreads();
        for (int i = tid; i < 1024; i += 256) {
            unsigned vv = lh[i];
            if (vv) atomicAdd(&rhist[i], vv);
        }
    }
    __threadfence();
    __syncthreads();
    if (tid == 0) tkt = atomicAdd(tick, 1u);
    __syncthreads();
    if (tkt != gridDim.x - 1) return;

    // ---- winner: parallel exact-threshold find ----
    if (B < 0) { if (tid == 0) *ptb = 0u; return; }
    unsigned CA = *pCA;
    unsigned gsum = 0;
    #pragma unroll
    for (int k = 0; k < 4; ++k) {
        unsigned bv = agent_load_u32(&rhist[tid * 4 + k]);
        rbin[tid * 4 + k] = bv; gsum += bv;
    }
    sgrp[tid] = gsum; ssfx[tid] = gsum;
    if (tid == 0) wg = -1;
    __syncthreads();
    #pragma unroll
    for (int off = 1; off < 256; off <<= 1) {
        unsigned a = (tid + off < 256) ? ssfx[tid + off] : 0u;
        __syncthreads();
        ssfx[tid] += a;
        __syncthreads();
    }
    unsigned incl = ssfx[tid], excl = incl - sgrp[tid];
    if (CA + excl < TOPK && CA + incl >= TOPK) { wg = tid; wcab = CA + excl; }
    __syncthreads();
    if (tid == 0) {
        int g = wg; unsigned sb = 0;
        if (g >= 0) {
            unsigned cab = wcab;
            for (int i = g * 4 + 3; i >= g * 4; --i) {
                unsigned cc = rbin[i];
                if (cab + cc >= TOPK) { sb = (unsigned)i; break; }
                cab += cc;
            }
        }
        *ptb = ((unsigned)(B + GH_BASE) << 19) | (sb << 9);
    }
}

// ------- K3: compact keys >= tb into sel2 (tb precomputed -> pure streaming) -------
__global__ __launch_bounds__(256) void k_select(
        const u64* __restrict__ sel, const unsigned* __restrict__ cnt,
        const unsigned* __restrict__ ptb,
        u64* __restrict__ sel2, unsigned* __restrict__ cnt2) {
    int tid = threadIdx.x, ln = tid & 63;
    unsigned tb = *ptb;
    unsigned M = *cnt; if (M > LISTCAP) M = LISTCAP;
    unsigned stride = gridDim.x * blockDim.x;
    for (unsigned ibase = blockIdx.x * blockDim.x; ibase < M; ibase += stride) {
        unsigned i = ibase + tid;
        bool act = (i < M);
        u64 key = act ? sel[i] : 0ull;
        bool c = act && ((unsigned)(key >> 32) >= tb);
        u64 b = __ballot(c);
        int n = __popcll(b);
        if (n == 0) continue;
        unsigned wb = 0;
        if (ln == 0) wb = atomicAdd(cnt2, (unsigned)n);
        wb = __shfl(wb, 0);
        if (c) {
            unsigned pos = wb + (unsigned)__popcll(b & ((1ull << ln) - 1ull));
            if (pos < CAP2) sel2[pos] = key;
        }
    }
}

// ------- K4: exact rank by counting + fused decode -------
__global__ __launch_bounds__(256) void k_rank_decode(
        const u64* __restrict__ sel2, const unsigned* __restrict__ cnt2,
        const float* __restrict__ boxes,
        float* __restrict__ boxK, float* __restrict__ scoreK, int* __restrict__ clsK) {
    __shared__ u64 ch[2048];
    unsigned S = *cnt2; if (S > CAP2) S = CAP2;
    unsigned t = blockIdx.x * 256u + threadIdx.x;
    if (blockIdx.x * 256u >= S) {                  // no ranking work in this block
        if (t < TOPK) {
            boxK[t * 4 + 0] = 0.0f; boxK[t * 4 + 1] = 0.0f;
            boxK[t * 4 + 2] = 0.0f; boxK[t * 4 + 3] = 0.0f;
            scoreK[t] = 0.0f; clsK[t] = -1;
        }
        return;
    }
    u64 my = (t < S) ? sel2[t] : 0ull;
    int r = 0;
    for (unsigned c0 = 0; c0 < S; c0 += 2048) {
        unsigned n = S - c0; if (n > 2048) n = 2048;
        __syncthreads();
        for (unsigned i = threadIdx.x; i < n; i += 256) ch[i] = sel2[c0 + i];
        __syncthreads();
        if (t < S)
            for (unsigned j = 0; j < n; j++) r += (ch[j] > my) ? 1 : 0;
    }
    if (t < S) {
        if (r < TOPK) {
            float sc = __uint_as_float((unsigned)(my >> 32));
            unsigned fi = 0xFFFFFFu - (unsigned)(my & 0xFFFFFFFFull);
            unsigned prop = fi / N_CLS;
            int cls = (int)(fi - prop * N_CLS);
            const float* b = boxes + (size_t)prop * 4;
            boxK[r * 4 + 0] = fminf(fmaxf(b[0], 0.0f), IMG_W - 1.0f);
            boxK[r * 4 + 1] = fminf(fmaxf(b[1], 0.0f), IMG_H - 1.0f);
            boxK[r * 4 + 2] = fminf(fmaxf(b[2], 0.0f), IMG_W - 1.0f);
            boxK[r * 4 + 3] = fminf(fmaxf(b[3], 0.0f), IMG_H - 1.0f);
            scoreK[r] = sc;
            clsK[r] = cls;
        }
    } else if (t < TOPK) {
        boxK[t * 4 + 0] = 0.0f; boxK[t * 4 + 1] = 0.0f;
        boxK[t * 4 + 2] = 0.0f; boxK[t * 4 + 3] = 0.0f;
        scoreK[t] = 0.0f; clsK[t] = -1;
    }
}

// ------- K5: conflict bit-matrix (IoU > 0.5 && same class), float4 loads -------
__global__ __launch_bounds__(256) void k_conflict(
        const float* __restrict__ boxK, const int* __restrict__ clsK,
        u64* __restrict__ mask) {
    int t = blockIdx.x * blockDim.x + threadIdx.x;
    if (t >= TOPK * 16) return;
    int i = t >> 4, w = t & 15;
    const float4* b4 = (const float4*)boxK;
    float4 bi = b4[i];
    int ci = clsK[i];
    float ai = (bi.z - bi.x) * (bi.w - bi.y);
    u64 m = 0;
    int jbase = w << 6;
    for (int jj = 0; jj < 64; jj++) {
        int j = jbase + jj;
        if (j >= TOPK) break;
        float4 bj = b4[j];
        float aj = (bj.z - bj.x) * (bj.w - bj.y);
        float ww = fmaxf(fminf(bi.z, bj.z) - fmaxf(bi.x, bj.x), 0.0f);
        float hh = fmaxf(fminf(bi.w, bj.w) - fmaxf(bi.y, bj.y), 0.0f);
        float inter = ww * hh;
        float iou = inter / (ai + aj - inter + 1e-9f);
        if (iou > 0.5f && ci == clsK[j]) m |= (1ull << jj);
    }
    mask[(size_t)i * 16 + w] = m;
}

// ------- K6: Jacobi fixed-point of the triangular greedy-NMS recurrence -------
__global__ __launch_bounds__(1024) void k_nms_out(
        const u64* __restrict__ mask, const float* __restrict__ boxK,
        const float* __restrict__ scoreK, float* __restrict__ out) {
    __shared__ u64 words[16];
    __shared__ int changed;
    int tid = threadIdx.x, wv = tid >> 6, ln = tid & 63;
    bool valid = (tid < TOPK) && (scoreK[tid] > 0.0f);
    u64 row[16];
    #pragma unroll
    for (int w = 0; w < 16; w++)
        row[w] = (tid < TOPK) ? mask[(size_t)tid * 16 + w] : 0ull;
    u64 lowmask = (1ull << ln) - 1ull;
    bool keep = valid;
    for (int it = 0; it < 1024; ++it) {
        u64 b = __ballot(keep);
        if (ln == 0) words[wv] = b;
        if (tid == 0) changed = 0;
        __syncthreads();
        u64 sup = 0;
        for (int w = 0; w <= wv; w++) {          // wv is wave-uniform
            u64 kw = words[w];
            if (w == wv) kw &= lowmask;
            sup |= row[w] & kw;
        }
        bool nk = valid && (sup == 0ull);
        if (nk != keep) changed = 1;
        keep = nk;
        __syncthreads();
        if (!changed) break;
    }
    if (tid < TOPK) {
        float x1 = boxK[tid * 4 + 0], y1 = boxK[tid * 4 + 1];
        float x2 = boxK[tid * 4 + 2], y2 = boxK[tid * 4 + 3];
        float sc = scoreK[tid];
        out[tid * 5 + 0] = keep ? x1 : 0.0f;
        out[tid * 5 + 1] = keep ? y1 : 0.0f;
        out[tid * 5 + 2] = keep ? x2 : 0.0f;
        out[tid * 5 + 3] = keep ? y2 : 0.0f;
        out[tid * 5 + 4] = keep ? sc : 0.0f;
    }
}

extern "C" void kernel_launch(void* const* d_in, const int* in_sizes, int n_in,
                              void* d_out, int out_size, void* d_ws, size_t ws_size,
                              hipStream_t stream) {
    const float* logits = (const float*)d_in[0];
    const float* boxes  = (const float*)d_in[1];
    float* out = (float*)d_out;
    int nrows = in_sizes[0] / N_CLS;   // 200000

    char* w = (char*)d_ws;
    unsigned* cnt    = (unsigned*)(w + OFF_CNT);
    unsigned* cnt2   = (unsigned*)(w + OFF_CNT2);
    unsigned* tick1  = (unsigned*)(w + OFF_TICK1);
    unsigned* tick2  = (unsigned*)(w + OFF_TICK2);
    int*      psB    = (int*)(w + OFF_SB);
    unsigned* pCA    = (unsigned*)(w + OFF_CA);
    unsigned* ptb    = (unsigned*)(w + OFF_TB);
    unsigned* ghist  = (unsigned*)(w + OFF_GH);
    unsigned* rhist  = (unsigned*)(w + OFF_RH);
    u64* sel         = (u64*)(w + OFF_SEL);
    u64* sel2        = (u64*)(w + OFF_SEL2);
    float* boxK      = (float*)(w + OFF_BOX);
    float* scoreK    = (float*)(w + OFF_SCORE);
    int* clsK        = (int*)(w + OFF_CLS);
    u64* mask        = (u64*)(w + OFF_MASK);

    hipMemsetAsync(w, 0, MEMSET_BYTES, stream);

    // 768 blocks = 3072 waves; 6250 groups -> ~2 groups/wave, grid-stride
    k_pass1<<<768, 256, 0, stream>>>(logits, nrows, sel, cnt, ghist, tick1, psB, pCA);
    k_refine<<<256, 256, 0, stream>>>(sel, cnt, rhist, tick2, psB, pCA, ptb);
    k_select<<<256, 256, 0, stream>>>(sel, cnt, ptb, sel2, cnt2);
    k_rank_decode<<<CAP2 / 256, 256, 0, stream>>>(sel2, cnt2, boxes, boxK, scoreK, clsK);
    k_conflict<<<(TOPK * 16 + 255) / 256, 256, 0, stream>>>(boxK, clsK, mask);
    k_nms_out<<<1, 1024, 0, stream>>>(mask, boxK, scoreK, out);
}